// Round 15
// baseline (50.038 us; speedup 1.0000x reference)
//
#include <hip/hip_runtime.h>
#include <stdint.h>

// ---- problem constants ----
#define S_LEN   2048
#define HIDDEN  768
#define NHEADS  12
#define QKV_LD  2304   // fused q|k|v row stride (elements)
#define NW      589824 // 768*768

typedef __attribute__((ext_vector_type(8))) short short8;
typedef __attribute__((ext_vector_type(4))) float f32x4;

typedef const __attribute__((address_space(1))) void* gas_ptr;
typedef __attribute__((address_space(3))) void* las_ptr;

__device__ __forceinline__ short f2b(float f) {
    union { float f; uint32_t u; } v; v.f = f;
    uint32_t u = v.u;
    uint32_t r = (u + 0x7FFFu + ((u >> 16) & 1u)) >> 16;
    return (short)r;
}

// ---------------- f32 -> bf16 converts: grid-stride, 1024 blocks (~1us) ----------------
__global__ __launch_bounds__(256)
void convert_all(const float* __restrict__ X,
                 const float* __restrict__ Wq, const float* __restrict__ Wk,
                 const float* __restrict__ Wv, const float* __restrict__ Wo,
                 short* __restrict__ Xb, short* __restrict__ Wqkvb,
                 short* __restrict__ Wob) {
    const int NX4 = 393216, NW4 = 147456, TOT = 983040;
    for (int idx = blockIdx.x * 256 + threadIdx.x; idx < TOT; idx += 1024 * 256) {
        const float* src; short* dst; int e;
        if (idx < NX4) {
            src = X; dst = Xb; e = idx * 4;
        } else {
            int j = idx - NX4;
            int wb = j / NW4, lb = j % NW4;
            src = wb == 0 ? Wq : wb == 1 ? Wk : wb == 2 ? Wv : Wo;
            dst = wb < 3 ? Wqkvb + wb * NW : Wob;
            e = lb * 4;
        }
        float4 v = *(const float4*)(src + e);
        *(short4*)(dst + e) = make_short4(f2b(v.x), f2b(v.y), f2b(v.z), f2b(v.w));
    }
}

// ========== Kernel 1: QKV GEMM, 64x128 tile, 3-buf counted-vmcnt pipeline ==========
// ISOLATED p2 TEST (R7 structure, qkv only): one s_barrier per K-step,
// vmcnt(6) keeps next stage's 6 loads in flight across the barrier.
__global__ __launch_bounds__(256)
void gemm_qkv(const short* __restrict__ A, const short* __restrict__ B,
              short* __restrict__ C) {
    __shared__ short sA[3][64 * 64];     // 8KB per buf
    __shared__ short sB[3][128 * 64];    // 16KB per buf  (72KB total)

    const int x = blockIdx.x & 7, i = blockIdx.x >> 3;   // i in [0,72)
    const int bm = (x >> 1) * 8 + i / 9;
    const int bn = (x & 1) * 9 + i % 9;

    const int tid = threadIdx.x, lane = tid & 63, w = tid >> 6;
    const int wr = w >> 1, wc = w & 1;

    f32x4 acc[2][4] = {};

    auto stage = [&](int buf, int k0) {
        #pragma unroll
        for (int c = 0; c < 2; ++c) {
            int r = w * 16 + c * 8 + (lane >> 3);
            int scb = ((lane & 7) * 16) ^ ((r & 7) << 4);
            const char* gp = (const char*)(A + (size_t)(bm * 64 + r) * 768 + k0) + scb;
            __builtin_amdgcn_global_load_lds((gas_ptr)gp,
                (las_ptr)((char*)&sA[buf][0] + w * 2048 + c * 1024), 16, 0, 0);
        }
        #pragma unroll
        for (int c = 0; c < 4; ++c) {
            int r = w * 32 + c * 8 + (lane >> 3);
            int scb = ((lane & 7) * 16) ^ ((r & 7) << 4);
            const char* gp = (const char*)(B + (size_t)(bn * 128 + r) * 768 + k0) + scb;
            __builtin_amdgcn_global_load_lds((gas_ptr)gp,
                (las_ptr)((char*)&sB[buf][0] + w * 4096 + c * 1024), 16, 0, 0);
        }
    };

    stage(0, 0);
    stage(1, 64);
    for (int t = 0; t < 12; ++t) {
        if (t < 11) asm volatile("s_waitcnt vmcnt(6)" ::: "memory");
        else        asm volatile("s_waitcnt vmcnt(0)" ::: "memory");
        __builtin_amdgcn_s_barrier();
        asm volatile("" ::: "memory");
        if (t < 10) stage((t + 2) % 3, (t + 2) * 64);

        const char* bA = (const char*)&sA[t % 3][0];
        const char* bB = (const char*)&sB[t % 3][0];
        #pragma unroll
        for (int kh = 0; kh < 2; ++kh) {
            const int kb = kh * 64 + ((lane >> 4) << 4);
            short8 av[2], bv[4];
            #pragma unroll
            for (int mi = 0; mi < 2; ++mi) {
                int row = wr * 32 + mi * 16 + (lane & 15);
                av[mi] = *(const short8*)(bA + row * 128 + (kb ^ ((row & 7) << 4)));
            }
            #pragma unroll
            for (int ni = 0; ni < 4; ++ni) {
                int row = wc * 64 + ni * 16 + (lane & 15);
                bv[ni] = *(const short8*)(bB + row * 128 + (kb ^ ((row & 7) << 4)));
            }
            #pragma unroll
            for (int mi = 0; mi < 2; ++mi)
                #pragma unroll
                for (int ni = 0; ni < 4; ++ni)
                    acc[mi][ni] = __builtin_amdgcn_mfma_f32_16x16x32_bf16(
                        av[mi], bv[ni], acc[mi][ni], 0, 0, 0);
        }
        asm volatile("" ::: "memory");
    }

    const int crow0 = bm * 64 + wr * 32;
    const int ccol0 = bn * 128 + wc * 64;
    #pragma unroll
    for (int mi = 0; mi < 2; ++mi)
        #pragma unroll
        for (int ni = 0; ni < 4; ++ni)
            #pragma unroll
            for (int r = 0; r < 4; ++r) {
                int grow = crow0 + mi * 16 + ((lane >> 4) << 2) + r;
                int gcol = ccol0 + ni * 16 + (lane & 15);
                C[(size_t)grow * QKV_LD + gcol] = f2b(acc[mi][ni][r]);
            }
}

// ========== Kernel 3: out GEMM, 64x64 tile, R6-style dbuf (R14-proven) ==========
__global__ __launch_bounds__(256)
void gemm_out(const short* __restrict__ A, const short* __restrict__ B,
              float* __restrict__ C) {
    __shared__ short sA[2][64 * 64];
    __shared__ short sB[2][64 * 64];

    const int x = blockIdx.x & 7, i = blockIdx.x >> 3;   // i in [0,48)
    const int bm = (x >> 1) * 8 + i / 6;
    const int bn = (x & 1) * 6 + i % 6;

    const int tid = threadIdx.x, lane = tid & 63, w = tid >> 6;
    const int wr = w >> 1, wc = w & 1;

    f32x4 acc[2][2] = {};

    auto stage = [&](int buf, int k0) {
        #pragma unroll
        for (int c = 0; c < 2; ++c) {
            int r = w * 16 + c * 8 + (lane >> 3);
            int scb = ((lane & 7) * 16) ^ ((r & 7) << 4);
            const char* gpA = (const char*)(A + (size_t)(bm * 64 + r) * 768 + k0) + scb;
            __builtin_amdgcn_global_load_lds((gas_ptr)gpA,
                (las_ptr)((char*)&sA[buf][0] + w * 2048 + c * 1024), 16, 0, 0);
            const char* gpB = (const char*)(B + (size_t)(bn * 64 + r) * 768 + k0) + scb;
            __builtin_amdgcn_global_load_lds((gas_ptr)gpB,
                (las_ptr)((char*)&sB[buf][0] + w * 2048 + c * 1024), 16, 0, 0);
        }
    };

    stage(0, 0);
    __syncthreads();
    int cur = 0;
    for (int t = 0; t < 12; ++t) {
        if (t < 11) stage(cur ^ 1, (t + 1) * 64);
        #pragma unroll
        for (int kh = 0; kh < 2; ++kh) {
            const int kb = kh * 64 + ((lane >> 4) << 4);
            short8 av[2], bv[2];
            #pragma unroll
            for (int mi = 0; mi < 2; ++mi) {
                int row = wr * 32 + mi * 16 + (lane & 15);
                av[mi] = *(const short8*)((const char*)&sA[cur][0] + row * 128 + (kb ^ ((row & 7) << 4)));
            }
            #pragma unroll
            for (int ni = 0; ni < 2; ++ni) {
                int row = wc * 32 + ni * 16 + (lane & 15);
                bv[ni] = *(const short8*)((const char*)&sB[cur][0] + row * 128 + (kb ^ ((row & 7) << 4)));
            }
            #pragma unroll
            for (int mi = 0; mi < 2; ++mi)
                #pragma unroll
                for (int ni = 0; ni < 2; ++ni)
                    acc[mi][ni] = __builtin_amdgcn_mfma_f32_16x16x32_bf16(
                        av[mi], bv[ni], acc[mi][ni], 0, 0, 0);
        }
        __syncthreads();
        cur ^= 1;
    }

    const int crow0 = bm * 64 + wr * 32;
    const int ccol0 = bn * 64 + wc * 32;
    #pragma unroll
    for (int mi = 0; mi < 2; ++mi)
        #pragma unroll
        for (int ni = 0; ni < 2; ++ni)
            #pragma unroll
            for (int r = 0; r < 4; ++r) {
                int grow = crow0 + mi * 16 + ((lane >> 4) << 2) + r;
                int gcol = ccol0 + ni * 16 + (lane & 15);
                C[(size_t)grow * HIDDEN + gcol] = acc[mi][ni][r];
            }
}

// ================= Kernel 2: MFMA sliding-window attention (R14 + T5 setprio) =====
__global__ __launch_bounds__(256)
void attn_mfma(const short* __restrict__ QKV, short* __restrict__ O) {
    __shared__ short sK[128 * 64];       // [kt][d]  swz, 16KB
    __shared__ short sVt[64 * 128];      // [d][kt]  swz, 16KB
    __shared__ short sP[4][16 * 128];    // per-wave [q][kt] swz, 16KB

    const int bid = blockIdx.x;                 // 384 = 8*48
    const int task = (bid & 7) * 48 + (bid >> 3);
    const int h = task % NHEADS;
    const int s0 = (task / NHEADS) * 64;
    const int tid = threadIdx.x, lane = tid & 63, w = tid >> 6;

    // ---- issue K stage first (4 gload_lds per wave), pin issue order ----
    #pragma unroll
    for (int c = 0; c < 4; ++c) {
        int r = (w * 4 + c) * 8 + (lane >> 3);
        int gr = s0 - 64 + r; if (gr < 0) gr = 0;
        int scb = ((lane & 7) * 16) ^ ((r & 7) << 4);
        const char* gp = (const char*)(QKV + (size_t)gr * QKV_LD + 768 + h * 64) + scb;
        __builtin_amdgcn_global_load_lds((gas_ptr)gp,
            (las_ptr)((char*)sK + (w * 4 + c) * 1024), 16, 0, 0);
    }
    __builtin_amdgcn_sched_barrier(0);

    // ---- Q fragments and V rows to registers (in flight across barrier) ----
    const int qrow = w * 16 + (lane & 15);
    short8 qf[2];
    #pragma unroll
    for (int kk = 0; kk < 2; ++kk)
        qf[kk] = *(const short8*)(QKV + (size_t)(s0 + qrow) * QKV_LD + h * 64
                                  + kk * 32 + ((lane >> 4) << 3));
    const int d0 = (tid & 7) * 8;
    const int kbase = (tid >> 3) * 4;
    short8 v[4];
    #pragma unroll
    for (int i = 0; i < 4; ++i) {
        int gr = s0 - 64 + kbase + i; if (gr < 0) gr = 0;
        v[i] = *(const short8*)(QKV + (size_t)gr * QKV_LD + 1536 + h * 64 + d0);
    }

    asm volatile("s_waitcnt vmcnt(6)" ::: "memory");
    __builtin_amdgcn_s_barrier();
    __builtin_amdgcn_sched_barrier(0);

    // ---- QK^T ----
    f32x4 s_acc[8];
    __builtin_amdgcn_s_setprio(1);
    #pragma unroll
    for (int ct = 0; ct < 8; ++ct) {
        s_acc[ct] = (f32x4){0.f, 0.f, 0.f, 0.f};
        int krow = ct * 16 + (lane & 15);
        #pragma unroll
        for (int kk = 0; kk < 2; ++kk) {
            int cb = kk * 64 + ((lane >> 4) << 4);
            short8 kf = *(const short8*)((const char*)sK + krow * 128 + (cb ^ ((krow & 7) << 4)));
            s_acc[ct] = __builtin_amdgcn_mfma_f32_16x16x32_bf16(qf[kk], kf, s_acc[ct], 0, 0, 0);
        }
    }
    __builtin_amdgcn_s_setprio(0);

    // ---- band mask + softmax (V still arriving underneath) ----
    const int kcol = lane & 15;
    const int qb = w * 16 + ((lane >> 4) << 2);
    float p[8][4];
    #pragma unroll
    for (int r = 0; r < 4; ++r) {
        int q = qb + r;
        float m = -1e30f;
        #pragma unroll
        for (int ct = 0; ct < 8; ++ct) {
            int kt = ct * 16 + kcol;
            bool valid = (kt > q) && (kt <= q + 64) && (s0 + kt >= 64);
            float sc = valid ? s_acc[ct][r] * 0.125f : -1e30f;
            p[ct][r] = sc;
            m = fmaxf(m, sc);
        }
        #pragma unroll
        for (int off = 1; off < 16; off <<= 1) m = fmaxf(m, __shfl_xor(m, off));
        float sm = 0.f;
        #pragma unroll
        for (int ct = 0; ct < 8; ++ct) {
            float e = __expf(p[ct][r] - m);
            p[ct][r] = e;
            sm += e;
        }
        #pragma unroll
        for (int off = 1; off < 16; off <<= 1) sm += __shfl_xor(sm, off);
        float inv = 1.f / sm;
        #pragma unroll
        for (int ct = 0; ct < 8; ++ct) p[ct][r] *= inv;
    }

    // ---- V transposed into sVt (j-rotated) ----
    #pragma unroll
    for (int j = 0; j < 8; ++j) {
        int jj = (j + tid) & 7;
        int row = d0 + jj;
        int b = row * 256 + ((kbase * 2) ^ ((row & 7) << 4));
        *(short4*)((char*)sVt + b) = make_short4(v[0][jj], v[1][jj], v[2][jj], v[3][jj]);
    }

    // ---- write P to per-wave swizzled LDS (wave-private) ----
    #pragma unroll
    for (int ct = 0; ct < 8; ++ct)
        #pragma unroll
        for (int r = 0; r < 4; ++r) {
            int row = ((lane >> 4) << 2) + r;
            int b = row * 256 + (((ct * 16 + kcol) * 2) ^ ((row & 7) << 4));
            *(short*)((char*)&sP[w][0] + b) = f2b(p[ct][r]);
        }

    __syncthreads();   // all waves' V writes visible before PV

    // ---- PV ----
    short8 pf[4];
    #pragma unroll
    for (int kk = 0; kk < 4; ++kk) {
        int row = lane & 15;
        int cb = kk * 64 + ((lane >> 4) << 4);
        pf[kk] = *(const short8*)((const char*)&sP[w][0] + row * 256 + (cb ^ ((row & 7) << 4)));
    }
    f32x4 o_acc[4];
    __builtin_amdgcn_s_setprio(1);
    #pragma unroll
    for (int nt = 0; nt < 4; ++nt) {
        o_acc[nt] = (f32x4){0.f, 0.f, 0.f, 0.f};
        #pragma unroll
        for (int kk = 0; kk < 4; ++kk) {
            int vrow = nt * 16 + (lane & 15);
            int cb = kk * 64 + ((lane >> 4) << 4);
            short8 vf = *(const short8*)((const char*)sVt + vrow * 256 + (cb ^ ((vrow & 7) << 4)));
            o_acc[nt] = __builtin_amdgcn_mfma_f32_16x16x32_bf16(pf[kk], vf, o_acc[nt], 0, 0, 0);
        }
    }
    __builtin_amdgcn_s_setprio(0);

    #pragma unroll
    for (int nt = 0; nt < 4; ++nt)
        #pragma unroll
        for (int r = 0; r < 4; ++r) {
            int q = s0 + qb + r;
            int dcol = h * 64 + nt * 16 + (lane & 15);
            O[(size_t)q * HIDDEN + dcol] = f2b(o_acc[nt][r]);
        }
}

// ---------------- launcher ----------------
extern "C" void kernel_launch(void* const* d_in, const int* in_sizes, int n_in,
                              void* d_out, int out_size, void* d_ws, size_t ws_size,
                              hipStream_t stream) {
    const float* X  = (const float*)d_in[0];
    const float* Wq = (const float*)d_in[1];
    const float* Wk = (const float*)d_in[2];
    const float* Wv = (const float*)d_in[3];
    const float* Wo = (const float*)d_in[4];
    float* out = (float*)d_out;

    char* ws = (char*)d_ws;
    short* Xb    = (short*)ws;                   // 2048*768   bf16
    short* Wqkvb = (short*)(ws + 3145728);       // 2304*768   bf16
    short* Wob   = (short*)(ws + 6684672);       // 768*768    bf16
    short* QKVb  = (short*)(ws + 7864320);       // 2048*2304  bf16
    short* Attnb = (short*)(ws + 17301504);      // 2048*768   bf16

    convert_all<<<1024, 256, 0, stream>>>(X, Wq, Wk, Wv, Wo, Xb, Wqkvb, Wob);
    gemm_qkv<<<576, 256, 0, stream>>>(Xb, Wqkvb, QKVb);
    attn_mfma<<<384, 256, 0, stream>>>(QKVb, Attnb);
    gemm_out<<<384, 256, 0, stream>>>(Attnb, Wob, out);
}

// Round 16
// 45.476 us; speedup vs baseline: 1.1003x; 1.1003x over previous
//
#include <hip/hip_runtime.h>
#include <stdint.h>

// ---- problem constants ----
#define S_LEN   2048
#define HIDDEN  768
#define NHEADS  12
#define QKV_LD  2304   // fused q|k|v row stride (elements)
#define NW      589824 // 768*768

typedef __attribute__((ext_vector_type(8))) short short8;
typedef __attribute__((ext_vector_type(4))) float f32x4;

typedef const __attribute__((address_space(1))) void* gas_ptr;
typedef __attribute__((address_space(3))) void* las_ptr;

__device__ __forceinline__ short f2b(float f) {
    union { float f; uint32_t u; } v; v.f = f;
    uint32_t u = v.u;
    uint32_t r = (u + 0x7FFFu + ((u >> 16) & 1u)) >> 16;
    return (short)r;
}

// ---------------- f32 -> bf16 converts: grid-stride, 1024 blocks (~1us) ----------------
__global__ __launch_bounds__(256)
void convert_all(const float* __restrict__ X,
                 const float* __restrict__ Wq, const float* __restrict__ Wk,
                 const float* __restrict__ Wv, const float* __restrict__ Wo,
                 short* __restrict__ Xb, short* __restrict__ Wqkvb,
                 short* __restrict__ Wob) {
    const int NX4 = 393216, NW4 = 147456, TOT = 983040;
    for (int idx = blockIdx.x * 256 + threadIdx.x; idx < TOT; idx += 1024 * 256) {
        const float* src; short* dst; int e;
        if (idx < NX4) {
            src = X; dst = Xb; e = idx * 4;
        } else {
            int j = idx - NX4;
            int wb = j / NW4, lb = j % NW4;
            src = wb == 0 ? Wq : wb == 1 ? Wk : wb == 2 ? Wv : Wo;
            dst = wb < 3 ? Wqkvb + wb * NW : Wob;
            e = lb * 4;
        }
        float4 v = *(const float4*)(src + e);
        *(short4*)(dst + e) = make_short4(f2b(v.x), f2b(v.y), f2b(v.z), f2b(v.w));
    }
}

// ========== Kernel 1: QKV GEMM, 128x128 tile A/B (R3-proven body, R6 dbuf) =====
// 288 blocks (16bm x 18bn), 64KB LDS, 4 waves each 64x64 (4x4 16x16 frags).
// Staged bytes 113MB vs 64x128's 169MB; 16 MFMA/wave per K-step vs 8.
__global__ __launch_bounds__(256)
void gemm_qkv(const short* __restrict__ A, const short* __restrict__ B,
              short* __restrict__ C) {
    __shared__ short sA[2][128 * 64];    // 16KB per buf
    __shared__ short sB[2][128 * 64];    // 16KB per buf  (64KB total)

    const int x = blockIdx.x & 7, i = blockIdx.x >> 3;   // i in [0,36)
    const int bm = (x >> 1) * 4 + i / 9;                 // 2D XCD chunk: 4bm x 9bn
    const int bn = (x & 1) * 9 + i % 9;

    const int tid = threadIdx.x, lane = tid & 63, w = tid >> 6;
    const int wr = w >> 1, wc = w & 1;

    f32x4 acc[4][4] = {};

    const int st_r_base = w * 32 + (lane >> 3);
    const int st_cb = (lane & 7) * 16;

    auto stage = [&](int buf, int k0) {
        #pragma unroll
        for (int c = 0; c < 4; ++c) {
            int r = st_r_base + c * 8;
            int scb = st_cb ^ ((r & 7) << 4);
            const char* gpA = (const char*)(A + (size_t)(bm * 128 + r) * 768 + k0) + scb;
            __builtin_amdgcn_global_load_lds((gas_ptr)gpA,
                (las_ptr)((char*)&sA[buf][0] + w * 4096 + c * 1024), 16, 0, 0);
            const char* gpB = (const char*)(B + (size_t)(bn * 128 + r) * 768 + k0) + scb;
            __builtin_amdgcn_global_load_lds((gas_ptr)gpB,
                (las_ptr)((char*)&sB[buf][0] + w * 4096 + c * 1024), 16, 0, 0);
        }
    };

    stage(0, 0);
    __syncthreads();
    int cur = 0;
    for (int t = 0; t < 12; ++t) {
        if (t < 11) stage(cur ^ 1, (t + 1) * 64);
        #pragma unroll
        for (int kh = 0; kh < 2; ++kh) {
            const int kb = kh * 64 + ((lane >> 4) << 4);
            short8 av[4], bv[4];
            #pragma unroll
            for (int mi = 0; mi < 4; ++mi) {
                int row = wr * 64 + mi * 16 + (lane & 15);
                av[mi] = *(const short8*)((const char*)&sA[cur][0] + row * 128 + (kb ^ ((row & 7) << 4)));
            }
            #pragma unroll
            for (int ni = 0; ni < 4; ++ni) {
                int row = wc * 64 + ni * 16 + (lane & 15);
                bv[ni] = *(const short8*)((const char*)&sB[cur][0] + row * 128 + (kb ^ ((row & 7) << 4)));
            }
            #pragma unroll
            for (int mi = 0; mi < 4; ++mi)
                #pragma unroll
                for (int ni = 0; ni < 4; ++ni)
                    acc[mi][ni] = __builtin_amdgcn_mfma_f32_16x16x32_bf16(
                        av[mi], bv[ni], acc[mi][ni], 0, 0, 0);
        }
        __syncthreads();
        cur ^= 1;
    }

    const int crow0 = bm * 128 + wr * 64;
    const int ccol0 = bn * 128 + wc * 64;
    #pragma unroll
    for (int mi = 0; mi < 4; ++mi)
        #pragma unroll
        for (int ni = 0; ni < 4; ++ni)
            #pragma unroll
            for (int r = 0; r < 4; ++r) {
                int grow = crow0 + mi * 16 + ((lane >> 4) << 2) + r;
                int gcol = ccol0 + ni * 16 + (lane & 15);
                C[(size_t)grow * QKV_LD + gcol] = f2b(acc[mi][ni][r]);
            }
}

// ========== Kernel 3: out GEMM, 64x64 tile, R6-style dbuf (R14-proven) ==========
__global__ __launch_bounds__(256)
void gemm_out(const short* __restrict__ A, const short* __restrict__ B,
              float* __restrict__ C) {
    __shared__ short sA[2][64 * 64];
    __shared__ short sB[2][64 * 64];

    const int x = blockIdx.x & 7, i = blockIdx.x >> 3;   // i in [0,48)
    const int bm = (x >> 1) * 8 + i / 6;
    const int bn = (x & 1) * 6 + i % 6;

    const int tid = threadIdx.x, lane = tid & 63, w = tid >> 6;
    const int wr = w >> 1, wc = w & 1;

    f32x4 acc[2][2] = {};

    auto stage = [&](int buf, int k0) {
        #pragma unroll
        for (int c = 0; c < 2; ++c) {
            int r = w * 16 + c * 8 + (lane >> 3);
            int scb = ((lane & 7) * 16) ^ ((r & 7) << 4);
            const char* gpA = (const char*)(A + (size_t)(bm * 64 + r) * 768 + k0) + scb;
            __builtin_amdgcn_global_load_lds((gas_ptr)gpA,
                (las_ptr)((char*)&sA[buf][0] + w * 2048 + c * 1024), 16, 0, 0);
            const char* gpB = (const char*)(B + (size_t)(bn * 64 + r) * 768 + k0) + scb;
            __builtin_amdgcn_global_load_lds((gas_ptr)gpB,
                (las_ptr)((char*)&sB[buf][0] + w * 2048 + c * 1024), 16, 0, 0);
        }
    };

    stage(0, 0);
    __syncthreads();
    int cur = 0;
    for (int t = 0; t < 12; ++t) {
        if (t < 11) stage(cur ^ 1, (t + 1) * 64);
        #pragma unroll
        for (int kh = 0; kh < 2; ++kh) {
            const int kb = kh * 64 + ((lane >> 4) << 4);
            short8 av[2], bv[2];
            #pragma unroll
            for (int mi = 0; mi < 2; ++mi) {
                int row = wr * 32 + mi * 16 + (lane & 15);
                av[mi] = *(const short8*)((const char*)&sA[cur][0] + row * 128 + (kb ^ ((row & 7) << 4)));
            }
            #pragma unroll
            for (int ni = 0; ni < 2; ++ni) {
                int row = wc * 32 + ni * 16 + (lane & 15);
                bv[ni] = *(const short8*)((const char*)&sB[cur][0] + row * 128 + (kb ^ ((row & 7) << 4)));
            }
            #pragma unroll
            for (int mi = 0; mi < 2; ++mi)
                #pragma unroll
                for (int ni = 0; ni < 2; ++ni)
                    acc[mi][ni] = __builtin_amdgcn_mfma_f32_16x16x32_bf16(
                        av[mi], bv[ni], acc[mi][ni], 0, 0, 0);
        }
        __syncthreads();
        cur ^= 1;
    }

    const int crow0 = bm * 64 + wr * 32;
    const int ccol0 = bn * 64 + wc * 32;
    #pragma unroll
    for (int mi = 0; mi < 2; ++mi)
        #pragma unroll
        for (int ni = 0; ni < 2; ++ni)
            #pragma unroll
            for (int r = 0; r < 4; ++r) {
                int grow = crow0 + mi * 16 + ((lane >> 4) << 2) + r;
                int gcol = ccol0 + ni * 16 + (lane & 15);
                C[(size_t)grow * HIDDEN + gcol] = acc[mi][ni][r];
            }
}

// ================= Kernel 2: MFMA sliding-window attention (R14-proven, no setprio) =====
__global__ __launch_bounds__(256)
void attn_mfma(const short* __restrict__ QKV, short* __restrict__ O) {
    __shared__ short sK[128 * 64];       // [kt][d]  swz, 16KB
    __shared__ short sVt[64 * 128];      // [d][kt]  swz, 16KB
    __shared__ short sP[4][16 * 128];    // per-wave [q][kt] swz, 16KB

    const int bid = blockIdx.x;                 // 384 = 8*48
    const int task = (bid & 7) * 48 + (bid >> 3);
    const int h = task % NHEADS;
    const int s0 = (task / NHEADS) * 64;
    const int tid = threadIdx.x, lane = tid & 63, w = tid >> 6;

    // ---- issue K stage first (4 gload_lds per wave), pin issue order ----
    #pragma unroll
    for (int c = 0; c < 4; ++c) {
        int r = (w * 4 + c) * 8 + (lane >> 3);
        int gr = s0 - 64 + r; if (gr < 0) gr = 0;
        int scb = ((lane & 7) * 16) ^ ((r & 7) << 4);
        const char* gp = (const char*)(QKV + (size_t)gr * QKV_LD + 768 + h * 64) + scb;
        __builtin_amdgcn_global_load_lds((gas_ptr)gp,
            (las_ptr)((char*)sK + (w * 4 + c) * 1024), 16, 0, 0);
    }
    __builtin_amdgcn_sched_barrier(0);

    // ---- Q fragments and V rows to registers (in flight across barrier) ----
    const int qrow = w * 16 + (lane & 15);
    short8 qf[2];
    #pragma unroll
    for (int kk = 0; kk < 2; ++kk)
        qf[kk] = *(const short8*)(QKV + (size_t)(s0 + qrow) * QKV_LD + h * 64
                                  + kk * 32 + ((lane >> 4) << 3));
    const int d0 = (tid & 7) * 8;
    const int kbase = (tid >> 3) * 4;
    short8 v[4];
    #pragma unroll
    for (int i = 0; i < 4; ++i) {
        int gr = s0 - 64 + kbase + i; if (gr < 0) gr = 0;
        v[i] = *(const short8*)(QKV + (size_t)gr * QKV_LD + 1536 + h * 64 + d0);
    }

    asm volatile("s_waitcnt vmcnt(6)" ::: "memory");
    __builtin_amdgcn_s_barrier();
    __builtin_amdgcn_sched_barrier(0);

    // ---- QK^T ----
    f32x4 s_acc[8];
    #pragma unroll
    for (int ct = 0; ct < 8; ++ct) {
        s_acc[ct] = (f32x4){0.f, 0.f, 0.f, 0.f};
        int krow = ct * 16 + (lane & 15);
        #pragma unroll
        for (int kk = 0; kk < 2; ++kk) {
            int cb = kk * 64 + ((lane >> 4) << 4);
            short8 kf = *(const short8*)((const char*)sK + krow * 128 + (cb ^ ((krow & 7) << 4)));
            s_acc[ct] = __builtin_amdgcn_mfma_f32_16x16x32_bf16(qf[kk], kf, s_acc[ct], 0, 0, 0);
        }
    }

    // ---- band mask + softmax (V still arriving underneath) ----
    const int kcol = lane & 15;
    const int qb = w * 16 + ((lane >> 4) << 2);
    float p[8][4];
    #pragma unroll
    for (int r = 0; r < 4; ++r) {
        int q = qb + r;
        float m = -1e30f;
        #pragma unroll
        for (int ct = 0; ct < 8; ++ct) {
            int kt = ct * 16 + kcol;
            bool valid = (kt > q) && (kt <= q + 64) && (s0 + kt >= 64);
            float sc = valid ? s_acc[ct][r] * 0.125f : -1e30f;
            p[ct][r] = sc;
            m = fmaxf(m, sc);
        }
        #pragma unroll
        for (int off = 1; off < 16; off <<= 1) m = fmaxf(m, __shfl_xor(m, off));
        float sm = 0.f;
        #pragma unroll
        for (int ct = 0; ct < 8; ++ct) {
            float e = __expf(p[ct][r] - m);
            p[ct][r] = e;
            sm += e;
        }
        #pragma unroll
        for (int off = 1; off < 16; off <<= 1) sm += __shfl_xor(sm, off);
        float inv = 1.f / sm;
        #pragma unroll
        for (int ct = 0; ct < 8; ++ct) p[ct][r] *= inv;
    }

    // ---- V transposed into sVt (j-rotated) ----
    #pragma unroll
    for (int j = 0; j < 8; ++j) {
        int jj = (j + tid) & 7;
        int row = d0 + jj;
        int b = row * 256 + ((kbase * 2) ^ ((row & 7) << 4));
        *(short4*)((char*)sVt + b) = make_short4(v[0][jj], v[1][jj], v[2][jj], v[3][jj]);
    }

    // ---- write P to per-wave swizzled LDS (wave-private) ----
    #pragma unroll
    for (int ct = 0; ct < 8; ++ct)
        #pragma unroll
        for (int r = 0; r < 4; ++r) {
            int row = ((lane >> 4) << 2) + r;
            int b = row * 256 + (((ct * 16 + kcol) * 2) ^ ((row & 7) << 4));
            *(short*)((char*)&sP[w][0] + b) = f2b(p[ct][r]);
        }

    __syncthreads();   // all waves' V writes visible before PV

    // ---- PV ----
    short8 pf[4];
    #pragma unroll
    for (int kk = 0; kk < 4; ++kk) {
        int row = lane & 15;
        int cb = kk * 64 + ((lane >> 4) << 4);
        pf[kk] = *(const short8*)((const char*)&sP[w][0] + row * 256 + (cb ^ ((row & 7) << 4)));
    }
    f32x4 o_acc[4];
    #pragma unroll
    for (int nt = 0; nt < 4; ++nt) {
        o_acc[nt] = (f32x4){0.f, 0.f, 0.f, 0.f};
        #pragma unroll
        for (int kk = 0; kk < 4; ++kk) {
            int vrow = nt * 16 + (lane & 15);
            int cb = kk * 64 + ((lane >> 4) << 4);
            short8 vf = *(const short8*)((const char*)sVt + vrow * 256 + (cb ^ ((vrow & 7) << 4)));
            o_acc[nt] = __builtin_amdgcn_mfma_f32_16x16x32_bf16(pf[kk], vf, o_acc[nt], 0, 0, 0);
        }
    }

    #pragma unroll
    for (int nt = 0; nt < 4; ++nt)
        #pragma unroll
        for (int r = 0; r < 4; ++r) {
            int q = s0 + qb + r;
            int dcol = h * 64 + nt * 16 + (lane & 15);
            O[(size_t)q * HIDDEN + dcol] = f2b(o_acc[nt][r]);
        }
}

// ---------------- launcher ----------------
extern "C" void kernel_launch(void* const* d_in, const int* in_sizes, int n_in,
                              void* d_out, int out_size, void* d_ws, size_t ws_size,
                              hipStream_t stream) {
    const float* X  = (const float*)d_in[0];
    const float* Wq = (const float*)d_in[1];
    const float* Wk = (const float*)d_in[2];
    const float* Wv = (const float*)d_in[3];
    const float* Wo = (const float*)d_in[4];
    float* out = (float*)d_out;

    char* ws = (char*)d_ws;
    short* Xb    = (short*)ws;                   // 2048*768   bf16
    short* Wqkvb = (short*)(ws + 3145728);       // 2304*768   bf16
    short* Wob   = (short*)(ws + 6684672);       // 768*768    bf16
    short* QKVb  = (short*)(ws + 7864320);       // 2048*2304  bf16
    short* Attnb = (short*)(ws + 17301504);      // 2048*768   bf16

    convert_all<<<1024, 256, 0, stream>>>(X, Wq, Wk, Wv, Wo, Xb, Wqkvb, Wob);
    gemm_qkv<<<288, 256, 0, stream>>>(Xb, Wqkvb, QKVb);      // 128x128 A/B
    attn_mfma<<<384, 256, 0, stream>>>(QKVb, Attnb);
    gemm_out<<<384, 256, 0, stream>>>(Attnb, Wob, out);
}

// Round 17
// 45.206 us; speedup vs baseline: 1.1069x; 1.0060x over previous
//
#include <hip/hip_runtime.h>
#include <stdint.h>

// ---- problem constants ----
#define S_LEN   2048
#define HIDDEN  768
#define NHEADS  12
#define QKV_LD  2304   // fused q|k|v row stride (elements)
#define NW      589824 // 768*768

typedef __attribute__((ext_vector_type(8))) short short8;
typedef __attribute__((ext_vector_type(4))) float f32x4;

typedef const __attribute__((address_space(1))) void* gas_ptr;
typedef __attribute__((address_space(3))) void* las_ptr;

__device__ __forceinline__ short f2b(float f) {
    union { float f; uint32_t u; } v; v.f = f;
    uint32_t u = v.u;
    uint32_t r = (u + 0x7FFFu + ((u >> 16) & 1u)) >> 16;
    return (short)r;
}

// ---------------- f32 -> bf16 converts: grid-stride, 1024 blocks (~1us) ----------------
__global__ __launch_bounds__(256)
void convert_all(const float* __restrict__ X,
                 const float* __restrict__ Wq, const float* __restrict__ Wk,
                 const float* __restrict__ Wv, const float* __restrict__ Wo,
                 short* __restrict__ Xb, short* __restrict__ Wqkvb,
                 short* __restrict__ Wob) {
    const int NX4 = 393216, NW4 = 147456, TOT = 983040;
    for (int idx = blockIdx.x * 256 + threadIdx.x; idx < TOT; idx += 1024 * 256) {
        const float* src; short* dst; int e;
        if (idx < NX4) {
            src = X; dst = Xb; e = idx * 4;
        } else {
            int j = idx - NX4;
            int wb = j / NW4, lb = j % NW4;
            src = wb == 0 ? Wq : wb == 1 ? Wk : wb == 2 ? Wv : Wo;
            dst = wb < 3 ? Wqkvb + wb * NW : Wob;
            e = lb * 4;
        }
        float4 v = *(const float4*)(src + e);
        *(short4*)(dst + e) = make_short4(f2b(v.x), f2b(v.y), f2b(v.z), f2b(v.w));
    }
}

// ========== Kernel 1: QKV GEMM, 128x128 tile (R16-proven best) ==========
__global__ __launch_bounds__(256)
void gemm_qkv(const short* __restrict__ A, const short* __restrict__ B,
              short* __restrict__ C) {
    __shared__ short sA[2][128 * 64];    // 16KB per buf
    __shared__ short sB[2][128 * 64];    // 16KB per buf  (64KB total)

    const int x = blockIdx.x & 7, i = blockIdx.x >> 3;   // i in [0,36)
    const int bm = (x >> 1) * 4 + i / 9;                 // 2D XCD chunk: 4bm x 9bn
    const int bn = (x & 1) * 9 + i % 9;

    const int tid = threadIdx.x, lane = tid & 63, w = tid >> 6;
    const int wr = w >> 1, wc = w & 1;

    f32x4 acc[4][4] = {};

    const int st_r_base = w * 32 + (lane >> 3);
    const int st_cb = (lane & 7) * 16;

    auto stage = [&](int buf, int k0) {
        #pragma unroll
        for (int c = 0; c < 4; ++c) {
            int r = st_r_base + c * 8;
            int scb = st_cb ^ ((r & 7) << 4);
            const char* gpA = (const char*)(A + (size_t)(bm * 128 + r) * 768 + k0) + scb;
            __builtin_amdgcn_global_load_lds((gas_ptr)gpA,
                (las_ptr)((char*)&sA[buf][0] + w * 4096 + c * 1024), 16, 0, 0);
            const char* gpB = (const char*)(B + (size_t)(bn * 128 + r) * 768 + k0) + scb;
            __builtin_amdgcn_global_load_lds((gas_ptr)gpB,
                (las_ptr)((char*)&sB[buf][0] + w * 4096 + c * 1024), 16, 0, 0);
        }
    };

    stage(0, 0);
    __syncthreads();
    int cur = 0;
    for (int t = 0; t < 12; ++t) {
        if (t < 11) stage(cur ^ 1, (t + 1) * 64);
        #pragma unroll
        for (int kh = 0; kh < 2; ++kh) {
            const int kb = kh * 64 + ((lane >> 4) << 4);
            short8 av[4], bv[4];
            #pragma unroll
            for (int mi = 0; mi < 4; ++mi) {
                int row = wr * 64 + mi * 16 + (lane & 15);
                av[mi] = *(const short8*)((const char*)&sA[cur][0] + row * 128 + (kb ^ ((row & 7) << 4)));
            }
            #pragma unroll
            for (int ni = 0; ni < 4; ++ni) {
                int row = wc * 64 + ni * 16 + (lane & 15);
                bv[ni] = *(const short8*)((const char*)&sB[cur][0] + row * 128 + (kb ^ ((row & 7) << 4)));
            }
            #pragma unroll
            for (int mi = 0; mi < 4; ++mi)
                #pragma unroll
                for (int ni = 0; ni < 4; ++ni)
                    acc[mi][ni] = __builtin_amdgcn_mfma_f32_16x16x32_bf16(
                        av[mi], bv[ni], acc[mi][ni], 0, 0, 0);
        }
        __syncthreads();
        cur ^= 1;
    }

    const int crow0 = bm * 128 + wr * 64;
    const int ccol0 = bn * 128 + wc * 64;
    #pragma unroll
    for (int mi = 0; mi < 4; ++mi)
        #pragma unroll
        for (int ni = 0; ni < 4; ++ni)
            #pragma unroll
            for (int r = 0; r < 4; ++r) {
                int grow = crow0 + mi * 16 + ((lane >> 4) << 2) + r;
                int gcol = ccol0 + ni * 16 + (lane & 15);
                C[(size_t)grow * QKV_LD + gcol] = f2b(acc[mi][ni][r]);
            }
}

// ========== Kernel 3: out GEMM, 64x64 tile, R6-style dbuf (R14-proven) ==========
__global__ __launch_bounds__(256)
void gemm_out(const short* __restrict__ A, const short* __restrict__ B,
              float* __restrict__ C) {
    __shared__ short sA[2][64 * 64];
    __shared__ short sB[2][64 * 64];

    const int x = blockIdx.x & 7, i = blockIdx.x >> 3;   // i in [0,48)
    const int bm = (x >> 1) * 8 + i / 6;
    const int bn = (x & 1) * 6 + i % 6;

    const int tid = threadIdx.x, lane = tid & 63, w = tid >> 6;
    const int wr = w >> 1, wc = w & 1;

    f32x4 acc[2][2] = {};

    auto stage = [&](int buf, int k0) {
        #pragma unroll
        for (int c = 0; c < 2; ++c) {
            int r = w * 16 + c * 8 + (lane >> 3);
            int scb = ((lane & 7) * 16) ^ ((r & 7) << 4);
            const char* gpA = (const char*)(A + (size_t)(bm * 64 + r) * 768 + k0) + scb;
            __builtin_amdgcn_global_load_lds((gas_ptr)gpA,
                (las_ptr)((char*)&sA[buf][0] + w * 2048 + c * 1024), 16, 0, 0);
            const char* gpB = (const char*)(B + (size_t)(bn * 64 + r) * 768 + k0) + scb;
            __builtin_amdgcn_global_load_lds((gas_ptr)gpB,
                (las_ptr)((char*)&sB[buf][0] + w * 2048 + c * 1024), 16, 0, 0);
        }
    };

    stage(0, 0);
    __syncthreads();
    int cur = 0;
    for (int t = 0; t < 12; ++t) {
        if (t < 11) stage(cur ^ 1, (t + 1) * 64);
        #pragma unroll
        for (int kh = 0; kh < 2; ++kh) {
            const int kb = kh * 64 + ((lane >> 4) << 4);
            short8 av[2], bv[2];
            #pragma unroll
            for (int mi = 0; mi < 2; ++mi) {
                int row = wr * 32 + mi * 16 + (lane & 15);
                av[mi] = *(const short8*)((const char*)&sA[cur][0] + row * 128 + (kb ^ ((row & 7) << 4)));
            }
            #pragma unroll
            for (int ni = 0; ni < 2; ++ni) {
                int row = wc * 32 + ni * 16 + (lane & 15);
                bv[ni] = *(const short8*)((const char*)&sB[cur][0] + row * 128 + (kb ^ ((row & 7) << 4)));
            }
            #pragma unroll
            for (int mi = 0; mi < 2; ++mi)
                #pragma unroll
                for (int ni = 0; ni < 2; ++ni)
                    acc[mi][ni] = __builtin_amdgcn_mfma_f32_16x16x32_bf16(
                        av[mi], bv[ni], acc[mi][ni], 0, 0, 0);
        }
        __syncthreads();
        cur ^= 1;
    }

    const int crow0 = bm * 64 + wr * 32;
    const int ccol0 = bn * 64 + wc * 32;
    #pragma unroll
    for (int mi = 0; mi < 2; ++mi)
        #pragma unroll
        for (int ni = 0; ni < 2; ++ni)
            #pragma unroll
            for (int r = 0; r < 4; ++r) {
                int grow = crow0 + mi * 16 + ((lane >> 4) << 2) + r;
                int gcol = ccol0 + ni * 16 + (lane & 15);
                C[(size_t)grow * HIDDEN + gcol] = acc[mi][ni][r];
            }
}

// ================= Kernel 2: MFMA sliding-window attention (R16 + T5 setprio) =====
__global__ __launch_bounds__(256)
void attn_mfma(const short* __restrict__ QKV, short* __restrict__ O) {
    __shared__ short sK[128 * 64];       // [kt][d]  swz, 16KB
    __shared__ short sVt[64 * 128];      // [d][kt]  swz, 16KB
    __shared__ short sP[4][16 * 128];    // per-wave [q][kt] swz, 16KB

    const int bid = blockIdx.x;                 // 384 = 8*48
    const int task = (bid & 7) * 48 + (bid >> 3);
    const int h = task % NHEADS;
    const int s0 = (task / NHEADS) * 64;
    const int tid = threadIdx.x, lane = tid & 63, w = tid >> 6;

    // ---- issue K stage first (4 gload_lds per wave), pin issue order ----
    #pragma unroll
    for (int c = 0; c < 4; ++c) {
        int r = (w * 4 + c) * 8 + (lane >> 3);
        int gr = s0 - 64 + r; if (gr < 0) gr = 0;
        int scb = ((lane & 7) * 16) ^ ((r & 7) << 4);
        const char* gp = (const char*)(QKV + (size_t)gr * QKV_LD + 768 + h * 64) + scb;
        __builtin_amdgcn_global_load_lds((gas_ptr)gp,
            (las_ptr)((char*)sK + (w * 4 + c) * 1024), 16, 0, 0);
    }
    __builtin_amdgcn_sched_barrier(0);

    // ---- Q fragments and V rows to registers (in flight across barrier) ----
    const int qrow = w * 16 + (lane & 15);
    short8 qf[2];
    #pragma unroll
    for (int kk = 0; kk < 2; ++kk)
        qf[kk] = *(const short8*)(QKV + (size_t)(s0 + qrow) * QKV_LD + h * 64
                                  + kk * 32 + ((lane >> 4) << 3));
    const int d0 = (tid & 7) * 8;
    const int kbase = (tid >> 3) * 4;
    short8 v[4];
    #pragma unroll
    for (int i = 0; i < 4; ++i) {
        int gr = s0 - 64 + kbase + i; if (gr < 0) gr = 0;
        v[i] = *(const short8*)(QKV + (size_t)gr * QKV_LD + 1536 + h * 64 + d0);
    }

    asm volatile("s_waitcnt vmcnt(6)" ::: "memory");
    __builtin_amdgcn_s_barrier();
    __builtin_amdgcn_sched_barrier(0);

    // ---- QK^T (setprio: favor MFMA wave vs other blocks' staging) ----
    f32x4 s_acc[8];
    __builtin_amdgcn_s_setprio(1);
    #pragma unroll
    for (int ct = 0; ct < 8; ++ct) {
        s_acc[ct] = (f32x4){0.f, 0.f, 0.f, 0.f};
        int krow = ct * 16 + (lane & 15);
        #pragma unroll
        for (int kk = 0; kk < 2; ++kk) {
            int cb = kk * 64 + ((lane >> 4) << 4);
            short8 kf = *(const short8*)((const char*)sK + krow * 128 + (cb ^ ((krow & 7) << 4)));
            s_acc[ct] = __builtin_amdgcn_mfma_f32_16x16x32_bf16(qf[kk], kf, s_acc[ct], 0, 0, 0);
        }
    }
    __builtin_amdgcn_s_setprio(0);

    // ---- band mask + softmax (V still arriving underneath) ----
    const int kcol = lane & 15;
    const int qb = w * 16 + ((lane >> 4) << 2);
    float p[8][4];
    #pragma unroll
    for (int r = 0; r < 4; ++r) {
        int q = qb + r;
        float m = -1e30f;
        #pragma unroll
        for (int ct = 0; ct < 8; ++ct) {
            int kt = ct * 16 + kcol;
            bool valid = (kt > q) && (kt <= q + 64) && (s0 + kt >= 64);
            float sc = valid ? s_acc[ct][r] * 0.125f : -1e30f;
            p[ct][r] = sc;
            m = fmaxf(m, sc);
        }
        #pragma unroll
        for (int off = 1; off < 16; off <<= 1) m = fmaxf(m, __shfl_xor(m, off));
        float sm = 0.f;
        #pragma unroll
        for (int ct = 0; ct < 8; ++ct) {
            float e = __expf(p[ct][r] - m);
            p[ct][r] = e;
            sm += e;
        }
        #pragma unroll
        for (int off = 1; off < 16; off <<= 1) sm += __shfl_xor(sm, off);
        float inv = 1.f / sm;
        #pragma unroll
        for (int ct = 0; ct < 8; ++ct) p[ct][r] *= inv;
    }

    // ---- V transposed into sVt (j-rotated) ----
    #pragma unroll
    for (int j = 0; j < 8; ++j) {
        int jj = (j + tid) & 7;
        int row = d0 + jj;
        int b = row * 256 + ((kbase * 2) ^ ((row & 7) << 4));
        *(short4*)((char*)sVt + b) = make_short4(v[0][jj], v[1][jj], v[2][jj], v[3][jj]);
    }

    // ---- write P to per-wave swizzled LDS (wave-private) ----
    #pragma unroll
    for (int ct = 0; ct < 8; ++ct)
        #pragma unroll
        for (int r = 0; r < 4; ++r) {
            int row = ((lane >> 4) << 2) + r;
            int b = row * 256 + (((ct * 16 + kcol) * 2) ^ ((row & 7) << 4));
            *(short*)((char*)&sP[w][0] + b) = f2b(p[ct][r]);
        }

    __syncthreads();   // all waves' V writes visible before PV

    // ---- PV (setprio around MFMA cluster) ----
    short8 pf[4];
    #pragma unroll
    for (int kk = 0; kk < 4; ++kk) {
        int row = lane & 15;
        int cb = kk * 64 + ((lane >> 4) << 4);
        pf[kk] = *(const short8*)((const char*)&sP[w][0] + row * 256 + (cb ^ ((row & 7) << 4)));
    }
    f32x4 o_acc[4];
    __builtin_amdgcn_s_setprio(1);
    #pragma unroll
    for (int nt = 0; nt < 4; ++nt) {
        o_acc[nt] = (f32x4){0.f, 0.f, 0.f, 0.f};
        #pragma unroll
        for (int kk = 0; kk < 4; ++kk) {
            int vrow = nt * 16 + (lane & 15);
            int cb = kk * 64 + ((lane >> 4) << 4);
            short8 vf = *(const short8*)((const char*)sVt + vrow * 256 + (cb ^ ((vrow & 7) << 4)));
            o_acc[nt] = __builtin_amdgcn_mfma_f32_16x16x32_bf16(pf[kk], vf, o_acc[nt], 0, 0, 0);
        }
    }
    __builtin_amdgcn_s_setprio(0);

    #pragma unroll
    for (int nt = 0; nt < 4; ++nt)
        #pragma unroll
        for (int r = 0; r < 4; ++r) {
            int q = s0 + qb + r;
            int dcol = h * 64 + nt * 16 + (lane & 15);
            O[(size_t)q * HIDDEN + dcol] = f2b(o_acc[nt][r]);
        }
}

// ---------------- launcher ----------------
extern "C" void kernel_launch(void* const* d_in, const int* in_sizes, int n_in,
                              void* d_out, int out_size, void* d_ws, size_t ws_size,
                              hipStream_t stream) {
    const float* X  = (const float*)d_in[0];
    const float* Wq = (const float*)d_in[1];
    const float* Wk = (const float*)d_in[2];
    const float* Wv = (const float*)d_in[3];
    const float* Wo = (const float*)d_in[4];
    float* out = (float*)d_out;

    char* ws = (char*)d_ws;
    short* Xb    = (short*)ws;                   // 2048*768   bf16
    short* Wqkvb = (short*)(ws + 3145728);       // 2304*768   bf16
    short* Wob   = (short*)(ws + 6684672);       // 768*768    bf16
    short* QKVb  = (short*)(ws + 7864320);       // 2048*2304  bf16
    short* Attnb = (short*)(ws + 17301504);      // 2048*768   bf16

    convert_all<<<1024, 256, 0, stream>>>(X, Wq, Wk, Wv, Wo, Xb, Wqkvb, Wob);
    gemm_qkv<<<288, 256, 0, stream>>>(Xb, Wqkvb, QKVb);
    attn_mfma<<<384, 256, 0, stream>>>(QKVb, Attnb);
    gemm_out<<<384, 256, 0, stream>>>(Attnb, Wob, out);
}